// Round 1
// baseline (316.298 us; speedup 1.0000x reference)
//
#include <hip/hip_runtime.h>
#include <math.h>

#define N_SEQ 384
#define DIM 512
#define BATCH 8
#define M_ROWS (BATCH * N_SEQ)   // 3072
#define QK_COLS (2 * DIM)        // 1024: cols 0..511 = q, 512..1023 = k

typedef short v8s __attribute__((ext_vector_type(8)));   // 8 bf16 (4 VGPRs)
typedef float v4f __attribute__((ext_vector_type(4)));   // MFMA f32 acc

__device__ inline unsigned short f2bf(float f) {
    union { float f; unsigned u; } c; c.f = f;
    unsigned u = c.u;
    u += 0x7fffu + ((u >> 16) & 1u);   // RNE (inputs finite)
    return (unsigned short)(u >> 16);
}

// ---------------------------------------------------------------------------
// Kernel 0: prep = cast h/Wq/Wk -> bf16  +  left/right GEMVs, fused.
// One wave per 512-elem row.  Wave-tasks 0..3071 = h rows (cast + GEMV),
// 3072..4095 = Wq/Wk rows (cast only).  Grid 1024 x 256.
// ---------------------------------------------------------------------------
__global__ __launch_bounds__(256) void prep(
    const float* __restrict__ h, const float* __restrict__ Wq,
    const float* __restrict__ Wk, const float* __restrict__ wlr,
    const float* __restrict__ blr, const float* __restrict__ wrl,
    const float* __restrict__ brl, unsigned short* __restrict__ h_bf,
    unsigned short* __restrict__ w_bf, float* __restrict__ left,
    float* __restrict__ right)
{
    const int wv = threadIdx.x >> 6, lane = threadIdx.x & 63;
    const int task = blockIdx.x * 4 + wv;          // 0..4095
    const float* src; unsigned short* dst;
    if (task < M_ROWS) {
        src = h + (size_t)task * DIM;
        dst = h_bf + (size_t)task * DIM;
    } else {
        const int r = task - M_ROWS;               // 0..1023
        src = (r < DIM) ? (Wq + (size_t)r * DIM) : (Wk + (size_t)(r - DIM) * DIM);
        dst = w_bf + (size_t)r * DIM;
    }
    const float4* s4 = (const float4*)src;
    const float4 v0 = s4[lane];        // elems lane*4 .. +3
    const float4 v1 = s4[lane + 64];   // elems 256+lane*4 .. +3
    ushort4 o0, o1;
    o0.x = f2bf(v0.x); o0.y = f2bf(v0.y); o0.z = f2bf(v0.z); o0.w = f2bf(v0.w);
    o1.x = f2bf(v1.x); o1.y = f2bf(v1.y); o1.z = f2bf(v1.z); o1.w = f2bf(v1.w);
    *(ushort4*)(dst + lane * 4)       = o0;
    *(ushort4*)(dst + 256 + lane * 4) = o1;
    if (task < M_ROWS) {
        const float4* wl4 = (const float4*)wlr;
        const float4* wr4 = (const float4*)wrl;
        const float4 a0 = wl4[lane], a1 = wl4[lane + 64];
        const float4 c0 = wr4[lane], c1 = wr4[lane + 64];
        float sl = v0.x * a0.x + v0.y * a0.y + v0.z * a0.z + v0.w * a0.w
                 + v1.x * a1.x + v1.y * a1.y + v1.z * a1.z + v1.w * a1.w;
        float sr = v0.x * c0.x + v0.y * c0.y + v0.z * c0.z + v0.w * c0.w
                 + v1.x * c1.x + v1.y * c1.y + v1.z * c1.z + v1.w * c1.w;
#pragma unroll
        for (int off = 32; off > 0; off >>= 1) {
            sl += __shfl_down(sl, off);
            sr += __shfl_down(sr, off);
        }
        if (lane == 0) {
            left[task]  = sl + blr[0];
            right[task] = sr + brl[0];
        }
    }
}

// ---------------------------------------------------------------------------
// Kernel 1: MFMA qk projection, 64x64 tile, BK=128.  Unchanged (known-good).
// Grid 48x16 = 768 blocks, 3 blocks/CU.  LDS rows padded to 40 bf16.
// ---------------------------------------------------------------------------
__global__ __launch_bounds__(256) void qk_gemm(
    const unsigned short* __restrict__ A,   // h_bf 3072x512
    const unsigned short* __restrict__ Bm,  // w_bf 1024x512
    const float* __restrict__ bq,
    unsigned short* __restrict__ C)         // qk_bf 3072x1024
{
    __shared__ unsigned short As[4][64][40];
    __shared__ unsigned short Bs[4][64][40];
    const int bm = blockIdx.x * 64;
    const int bn = blockIdx.y * 64;
    const int t = threadIdx.x;
    const int wv = t >> 6, lane = t & 63;
    const int wm = (wv & 1) * 32, wn = (wv >> 1) * 32;
    const int lm = lane & 15, quad = lane >> 4;
    const int srow = t >> 2, skc = (t & 3) * 8;
    v4f acc[2][2] = {};
    for (int k0 = 0; k0 < DIM; k0 += 128) {
        const unsigned short* ap = A  + (size_t)(bm + srow) * DIM + k0 + skc;
        const unsigned short* bp = Bm + (size_t)(bn + srow) * DIM + k0 + skc;
        v8s a[4], b[4];
#pragma unroll
        for (int q = 0; q < 4; ++q) {
            a[q] = *(const v8s*)(ap + q * 32);
            b[q] = *(const v8s*)(bp + q * 32);
        }
        __syncthreads();
#pragma unroll
        for (int q = 0; q < 4; ++q) {
            *(v8s*)&As[q][srow][skc] = a[q];
            *(v8s*)&Bs[q][srow][skc] = b[q];
        }
        __syncthreads();
#pragma unroll
        for (int half = 0; half < 4; ++half) {
            v8s af[2], bf[2];
#pragma unroll
            for (int i = 0; i < 2; ++i) af[i] = *(const v8s*)&As[half][wm + i * 16 + lm][quad * 8];
#pragma unroll
            for (int j = 0; j < 2; ++j) bf[j] = *(const v8s*)&Bs[half][wn + j * 16 + lm][quad * 8];
#pragma unroll
            for (int i = 0; i < 2; ++i)
#pragma unroll
                for (int j = 0; j < 2; ++j)
                    acc[i][j] = __builtin_amdgcn_mfma_f32_16x16x32_bf16(af[i], bf[j], acc[i][j], 0, 0, 0);
        }
    }
#pragma unroll
    for (int i = 0; i < 2; ++i)
#pragma unroll
        for (int j = 0; j < 2; ++j) {
            const int col = bn + wn + j * 16 + lm;
            const float bias = (col < DIM) ? bq[col] : 0.f;
#pragma unroll
            for (int r = 0; r < 4; ++r) {
                const int row = bm + wm + i * 16 + quad * 4 + r;
                C[(size_t)row * QK_COLS + col] = f2bf(acc[i][j][r] + bias);
            }
        }
}

// ---------------------------------------------------------------------------
// Kernel 2 (NEW): fused scores + d-term + clip + log-sigmoid prefix scan +
// analytic mask-interval finalize.  One block per 16 rows x all 384 cols:
// grid (24, 8) = 192 blocks, 256 thr = 4 waves, wave owns a 96-col strip.
//  - q tile (16x512 bf16) staged once in LDS, 16B-chunk XOR swizzle
//    (row stride 1024B is bank-degenerate otherwise).
//  - B-frags (k rows) read directly from global: qk_bf is L2/L3-hot and
//    each k row feeds exactly one wave -> LDS staging would be pure overhead.
//  - scores live in 6 acc frags per wave (full 96-col strip in regs),
//    epilogue applied, dropped into sp[16][385] (stride 385 -> conflict-free
//    column reads), then each wave scans its 4 rows in place (prefix P
//    overwrites the score row; x values are already in registers).
// Eliminates the raw buffer (9 MB round-trip) and one launch.
// ---------------------------------------------------------------------------
__global__ __launch_bounds__(256) void score_final(
    const unsigned short* __restrict__ QK, const float* __restrict__ left,
    const float* __restrict__ right, const float* __restrict__ alpha,
    const float* __restrict__ beta, const float* __restrict__ gamma,
    const float* __restrict__ mask, float* __restrict__ out_r,
    float* __restrict__ out_am)
{
    __shared__ unsigned short q_lds[16 * 512];   // 16 KB, swizzled
    __shared__ float sp[16][N_SEQ + 1];          // scores, then prefix P
    const int b  = blockIdx.y;
    const int i0 = blockIdx.x * 16;
    const int t = threadIdx.x;
    const int wv = t >> 6, lane = t & 63;
    const int lm = lane & 15, quad = lane >> 4;
    const int wn = wv * 96;

    // ---- stage q rows i0..i0+15 (cols 0..511) into LDS, coalesced ----
#pragma unroll
    for (int it = 0; it < 4; ++it) {
        const int ch  = t + 256 * it;            // 16B chunk id, 0..1023
        const int row = ch >> 6, c = ch & 63;
        const v8s v = *(const v8s*)(QK + (size_t)(b * N_SEQ + i0 + row) * QK_COLS + c * 8);
        *(v8s*)&q_lds[row * 512 + ((c ^ (row & 7)) << 3)] = v;
    }
    __syncthreads();

    // ---- GEMM: scores[i0..i0+16) x cols [wn, wn+96), K = 512 ----
    const unsigned short* kb = QK + (size_t)(b * N_SEQ) * QK_COLS + DIM;
    const unsigned short* kr[6];
#pragma unroll
    for (int j = 0; j < 6; ++j)
        kr[j] = kb + (size_t)(wn + j * 16 + lm) * QK_COLS + quad * 8;

    v4f acc[6] = {};
    v8s bc[6];
#pragma unroll
    for (int j = 0; j < 6; ++j) bc[j] = *(const v8s*)(kr[j]);
#pragma unroll
    for (int ks = 0; ks < 16; ++ks) {
        v8s bn[6];
        if (ks < 15) {
#pragma unroll
            for (int j = 0; j < 6; ++j) bn[j] = *(const v8s*)(kr[j] + (ks + 1) * 32);
        }
        const v8s af = *(const v8s*)&q_lds[lm * 512 + ((((ks << 2) + quad) ^ (lm & 7)) << 3)];
#pragma unroll
        for (int j = 0; j < 6; ++j)
            acc[j] = __builtin_amdgcn_mfma_f32_16x16x32_bf16(af, bc[j], acc[j], 0, 0, 0);
        if (ks < 15) {
#pragma unroll
            for (int j = 0; j < 6; ++j) bc[j] = bn[j];
        }
    }

    // ---- epilogue: raw = clip(alpha*s + beta*d + gamma) -> sp ----
    const float al = alpha[0], be = beta[0], ga = gamma[0];
    float lvr[4], rvr[4];
#pragma unroll
    for (int r = 0; r < 4; ++r) {
        lvr[r] = left [b * N_SEQ + i0 + quad * 4 + r];
        rvr[r] = right[b * N_SEQ + i0 + quad * 4 + r];
    }
#pragma unroll
    for (int j = 0; j < 6; ++j) {
        const int jcol = wn + j * 16 + lm;
#pragma unroll
        for (int r = 0; r < 4; ++r) {
            const int gi = i0 + quad * 4 + r;
            const float dterm = (jcol >= gi) ? lvr[r] : rvr[r];
            float v = fmaf(al, acc[j][r], fmaf(be, dterm, ga));
            v = fminf(fmaxf(v, -16.f), 14.f);
            sp[quad * 4 + r][jcol] = v;
        }
    }
    __syncthreads();

    // ---- per-row scan + intervals; wave wv owns rows wv*4 .. wv*4+3 ----
    for (int rr = 0; rr < 4; ++rr) {
        const int irow = wv * 4 + rr;
        const int gi = i0 + irow;
        float x[6], l1[6];
#pragma unroll
        for (int c = 0; c < 6; ++c) {
            x[c]  = sp[irow][c * 64 + lane];
            l1[c] = -log1pf(expf(x[c]));     // log(1 - sigmoid(x))
        }
        // segmented inclusive scan -> exclusive prefix P over the row,
        // written in place over the (now register-resident) score row.
        float base = 0.f;
#pragma unroll
        for (int c = 0; c < 6; ++c) {
            float incl = l1[c];
#pragma unroll
            for (int off = 1; off < 64; off <<= 1) {
                const float tt = __shfl_up(incl, off);
                if (lane >= off) incl += tt;
            }
            sp[irow][1 + c * 64 + lane] = base + incl;
            base += __shfl(incl, 63);        // segment total broadcast
        }
        if (lane == 0) sp[irow][0] = 0.f;
        asm volatile("" ::: "memory");       // order in-wave P writes vs reads

        const float mi = mask[b * N_SEQ + gi];
        const float* P = sp[irow];
#pragma unroll
        for (int c = 0; c < 6; ++c) {
            const int j = c * 64 + lane;
            float s = 0.f;
            if (gi < j) {
                int lo2 = 2 * gi - j + 1; if (lo2 < 0) lo2 = 0;
                s = (P[j] - P[gi + 1]) + (P[gi] - P[lo2]);
            } else if (gi > j) {
                int hi2 = 2 * gi - j + 1; if (hi2 > N_SEQ) hi2 = N_SEQ;
                s = (P[gi] - P[j + 1]) + (P[hi2] - P[gi + 1]);
            }
            float r = s + (x[c] + l1[c]);    // lp = x + l1
            if (gi == j) r -= 10000.f;
            const size_t o = ((size_t)b * N_SEQ + gi) * N_SEQ + j;
            out_r[o]  = r;
            out_am[o] = mi * mask[b * N_SEQ + j];
        }
    }
}

// ---------------------------------------------------------------------------
extern "C" void kernel_launch(void* const* d_in, const int* in_sizes, int n_in,
                              void* d_out, int out_size, void* d_ws, size_t ws_size,
                              hipStream_t stream) {
    const float* h     = (const float*)d_in[0];
    const float* mask  = (const float*)d_in[1];
    const float* Wq    = (const float*)d_in[2];
    const float* bq    = (const float*)d_in[3];
    const float* Wk    = (const float*)d_in[4];
    const float* wlr   = (const float*)d_in[5];
    const float* blr   = (const float*)d_in[6];
    const float* wrl   = (const float*)d_in[7];
    const float* brl   = (const float*)d_in[8];
    const float* alpha = (const float*)d_in[9];
    const float* beta  = (const float*)d_in[10];
    const float* gamma = (const float*)d_in[11];
    // d_in[12] (masking_matrix) intentionally unused: analytic k-intervals +
    // prefix sum replace the O(N^3) einsum.

    unsigned short* h_bf  = (unsigned short*)d_ws;                 // 3072x512
    unsigned short* w_bf  = h_bf + (size_t)M_ROWS * DIM;           // 1024x512
    unsigned short* qk_bf = w_bf + (size_t)QK_COLS * DIM;          // 3072x1024
    float* left  = (float*)(qk_bf + (size_t)M_ROWS * QK_COLS);     // 3072
    float* right = left + M_ROWS;                                  // 3072
    // raw buffer eliminated (score+finalize fused)

    float* out_r  = (float*)d_out;
    float* out_am = out_r + (size_t)BATCH * N_SEQ * N_SEQ;

    prep<<<1024, 256, 0, stream>>>(h, Wq, Wk, wlr, blr, wrl, brl,
                                   h_bf, w_bf, left, right);
    dim3 g1(M_ROWS / 64, QK_COLS / 64);         // 48 x 16
    qk_gemm<<<g1, 256, 0, stream>>>(h_bf, w_bf, bq, qk_bf);
    dim3 g2(N_SEQ / 16, BATCH);                 // 24 x 8
    score_final<<<g2, 256, 0, stream>>>(qk_bf, left, right, alpha, beta, gamma,
                                        mask, out_r, out_am);
}

// Round 2
// 302.687 us; speedup vs baseline: 1.0450x; 1.0450x over previous
//
#include <hip/hip_runtime.h>
#include <math.h>

#define N_SEQ 384
#define DIM 512
#define BATCH 8
#define M_ROWS (BATCH * N_SEQ)   // 3072
#define QK_COLS (2 * DIM)        // 1024: cols 0..511 = q, 512..1023 = k

typedef short v8s __attribute__((ext_vector_type(8)));   // 8 bf16 (4 VGPRs)
typedef float v4f __attribute__((ext_vector_type(4)));   // MFMA f32 acc

__device__ inline unsigned short f2bf(float f) {
    union { float f; unsigned u; } c; c.f = f;
    unsigned u = c.u;
    u += 0x7fffu + ((u >> 16) & 1u);   // RNE (inputs finite)
    return (unsigned short)(u >> 16);
}

// ---------------------------------------------------------------------------
// Kernel 0: prep = cast h/Wq/Wk -> bf16  +  left/right GEMVs, fused.
// One wave per 512-elem row.  Wave-tasks 0..3071 = h rows (cast + GEMV),
// 3072..4095 = Wq/Wk rows (cast only).  Grid 1024 x 256.  (known-good)
// ---------------------------------------------------------------------------
__global__ __launch_bounds__(256) void prep(
    const float* __restrict__ h, const float* __restrict__ Wq,
    const float* __restrict__ Wk, const float* __restrict__ wlr,
    const float* __restrict__ blr, const float* __restrict__ wrl,
    const float* __restrict__ brl, unsigned short* __restrict__ h_bf,
    unsigned short* __restrict__ w_bf, float* __restrict__ left,
    float* __restrict__ right)
{
    const int wv = threadIdx.x >> 6, lane = threadIdx.x & 63;
    const int task = blockIdx.x * 4 + wv;          // 0..4095
    const float* src; unsigned short* dst;
    if (task < M_ROWS) {
        src = h + (size_t)task * DIM;
        dst = h_bf + (size_t)task * DIM;
    } else {
        const int r = task - M_ROWS;               // 0..1023
        src = (r < DIM) ? (Wq + (size_t)r * DIM) : (Wk + (size_t)(r - DIM) * DIM);
        dst = w_bf + (size_t)r * DIM;
    }
    const float4* s4 = (const float4*)src;
    const float4 v0 = s4[lane];        // elems lane*4 .. +3
    const float4 v1 = s4[lane + 64];   // elems 256+lane*4 .. +3
    ushort4 o0, o1;
    o0.x = f2bf(v0.x); o0.y = f2bf(v0.y); o0.z = f2bf(v0.z); o0.w = f2bf(v0.w);
    o1.x = f2bf(v1.x); o1.y = f2bf(v1.y); o1.z = f2bf(v1.z); o1.w = f2bf(v1.w);
    *(ushort4*)(dst + lane * 4)       = o0;
    *(ushort4*)(dst + 256 + lane * 4) = o1;
    if (task < M_ROWS) {
        const float4* wl4 = (const float4*)wlr;
        const float4* wr4 = (const float4*)wrl;
        const float4 a0 = wl4[lane], a1 = wl4[lane + 64];
        const float4 c0 = wr4[lane], c1 = wr4[lane + 64];
        float sl = v0.x * a0.x + v0.y * a0.y + v0.z * a0.z + v0.w * a0.w
                 + v1.x * a1.x + v1.y * a1.y + v1.z * a1.z + v1.w * a1.w;
        float sr = v0.x * c0.x + v0.y * c0.y + v0.z * c0.z + v0.w * c0.w
                 + v1.x * c1.x + v1.y * c1.y + v1.z * c1.z + v1.w * c1.w;
#pragma unroll
        for (int off = 32; off > 0; off >>= 1) {
            sl += __shfl_down(sl, off);
            sr += __shfl_down(sr, off);
        }
        if (lane == 0) {
            left[task]  = sl + blr[0];
            right[task] = sr + brl[0];
        }
    }
}

// ---------------------------------------------------------------------------
// Kernel 1: MFMA qk projection, 64x64 tile, BK=128.
// NEW: global_load_lds (16B) direct staging, linear [64][128] LDS with
// chunk XOR-swizzle  c_st = c_log ^ (row&7)  applied on the GLOBAL source
// (rule #21: inverse-swz source + swz read; HW writes base + lane*16).
// Eliminates 8 ds_write_b128 + VGPR round-trip per thread per K-slab.
// Bank math: frag ds_read_b128 -> 8 lanes per 16B chunk-col, 8 dwords/bank
// = b128 throughput floor.  LDS 32 KB (was 41).  Grid 48x16 = 768 blocks.
// ---------------------------------------------------------------------------
__global__ __launch_bounds__(256) void qk_gemm(
    const unsigned short* __restrict__ A,   // h_bf 3072x512
    const unsigned short* __restrict__ Bm,  // w_bf 1024x512
    const float* __restrict__ bq,
    unsigned short* __restrict__ C)         // qk_bf 3072x1024
{
    __shared__ unsigned short As[64 * 128];
    __shared__ unsigned short Bs[64 * 128];
    const int bm = blockIdx.x * 64;
    const int bn = blockIdx.y * 64;
    const int t = threadIdx.x;
    const int wv = t >> 6, lane = t & 63;
    const int wm = (wv & 1) * 32, wn = (wv >> 1) * 32;
    const int lm = lane & 15, quad = lane >> 4;
    // staging geometry: wave wv stages rows [wv*16, wv*16+16); per issue i,
    // lane covers row wv*16+i*4+(lane>>4), stored chunk c_dst = lane&15.
    const int sbase = wv * 16;
    const int rsub  = lane >> 4;
    const int cdst  = lane & 15;
    v4f acc[2][2] = {};
    for (int k0 = 0; k0 < DIM; k0 += 128) {
        __syncthreads();   // previous slab's reads done before overwrite
#pragma unroll
        for (int i = 0; i < 4; ++i) {
            const int row  = sbase + i * 4 + rsub;
            const int clog = cdst ^ (row & 7);
            const unsigned short* ga = A  + (size_t)(bm + row) * DIM + k0 + clog * 8;
            const unsigned short* gb = Bm + (size_t)(bn + row) * DIM + k0 + clog * 8;
            __builtin_amdgcn_global_load_lds(
                (const __attribute__((address_space(1))) unsigned*)ga,
                (__attribute__((address_space(3))) unsigned*)&As[(sbase + i * 4) * 128],
                16, 0, 0);
            __builtin_amdgcn_global_load_lds(
                (const __attribute__((address_space(1))) unsigned*)gb,
                (__attribute__((address_space(3))) unsigned*)&Bs[(sbase + i * 4) * 128],
                16, 0, 0);
        }
        __syncthreads();   // barrier drain (vmcnt 0) -> LDS ready
#pragma unroll
        for (int h = 0; h < 4; ++h) {
            v8s af[2], bf[2];
#pragma unroll
            for (int i = 0; i < 2; ++i) {
                const int r = wm + i * 16 + lm;
                af[i] = *(const v8s*)&As[r * 128 + (((h * 4 + quad) ^ (r & 7)) << 3)];
            }
#pragma unroll
            for (int j = 0; j < 2; ++j) {
                const int r = wn + j * 16 + lm;
                bf[j] = *(const v8s*)&Bs[r * 128 + (((h * 4 + quad) ^ (r & 7)) << 3)];
            }
#pragma unroll
            for (int i = 0; i < 2; ++i)
#pragma unroll
                for (int j = 0; j < 2; ++j)
                    acc[i][j] = __builtin_amdgcn_mfma_f32_16x16x32_bf16(af[i], bf[j], acc[i][j], 0, 0, 0);
        }
    }
#pragma unroll
    for (int i = 0; i < 2; ++i)
#pragma unroll
        for (int j = 0; j < 2; ++j) {
            const int col = bn + wn + j * 16 + lm;
            const float bias = (col < DIM) ? bq[col] : 0.f;
#pragma unroll
            for (int r = 0; r < 4; ++r) {
                const int row = bm + wm + i * 16 + quad * 4 + r;
                C[(size_t)row * QK_COLS + col] = f2bf(acc[i][j][r] + bias);
            }
        }
}

// ---------------------------------------------------------------------------
// Kernel 2: MFMA batched scores q_b @ k_b^T fused with
// raw = clip(alpha*s + beta*d + gamma).  64x64 tile, BK=128, grid 6x6x8=288.
// Same global_load_lds swizzled staging as qk_gemm.
// ---------------------------------------------------------------------------
__global__ __launch_bounds__(256) void score_gemm(
    const unsigned short* __restrict__ QK, const float* __restrict__ left,
    const float* __restrict__ right, const float* __restrict__ alpha,
    const float* __restrict__ beta, const float* __restrict__ gamma,
    float* __restrict__ raw)
{
    __shared__ unsigned short As[64 * 128];
    __shared__ unsigned short Bs[64 * 128];
    const int b  = blockIdx.z;
    const int bi = blockIdx.x * 64, bj = blockIdx.y * 64;
    const int t = threadIdx.x;
    const int wv = t >> 6, lane = t & 63;
    const int wm = (wv & 1) * 32, wn = (wv >> 1) * 32;
    const int lm = lane & 15, quad = lane >> 4;
    const int sbase = wv * 16;
    const int rsub  = lane >> 4;
    const int cdst  = lane & 15;
    const unsigned short* qb = QK + (size_t)(b * N_SEQ) * QK_COLS;
    v4f acc[2][2] = {};
    for (int k0 = 0; k0 < DIM; k0 += 128) {
        __syncthreads();
#pragma unroll
        for (int i = 0; i < 4; ++i) {
            const int row  = sbase + i * 4 + rsub;
            const int clog = cdst ^ (row & 7);
            const unsigned short* ga = qb + (size_t)(bi + row) * QK_COLS + k0 + clog * 8;
            const unsigned short* gb = qb + (size_t)(bj + row) * QK_COLS + DIM + k0 + clog * 8;
            __builtin_amdgcn_global_load_lds(
                (const __attribute__((address_space(1))) unsigned*)ga,
                (__attribute__((address_space(3))) unsigned*)&As[(sbase + i * 4) * 128],
                16, 0, 0);
            __builtin_amdgcn_global_load_lds(
                (const __attribute__((address_space(1))) unsigned*)gb,
                (__attribute__((address_space(3))) unsigned*)&Bs[(sbase + i * 4) * 128],
                16, 0, 0);
        }
        __syncthreads();
#pragma unroll
        for (int h = 0; h < 4; ++h) {
            v8s af[2], bf[2];
#pragma unroll
            for (int i = 0; i < 2; ++i) {
                const int r = wm + i * 16 + lm;
                af[i] = *(const v8s*)&As[r * 128 + (((h * 4 + quad) ^ (r & 7)) << 3)];
            }
#pragma unroll
            for (int j = 0; j < 2; ++j) {
                const int r = wn + j * 16 + lm;
                bf[j] = *(const v8s*)&Bs[r * 128 + (((h * 4 + quad) ^ (r & 7)) << 3)];
            }
#pragma unroll
            for (int i = 0; i < 2; ++i)
#pragma unroll
                for (int j = 0; j < 2; ++j)
                    acc[i][j] = __builtin_amdgcn_mfma_f32_16x16x32_bf16(af[i], bf[j], acc[i][j], 0, 0, 0);
        }
    }
    const float al = alpha[0], be = beta[0], ga = gamma[0];
#pragma unroll
    for (int i = 0; i < 2; ++i)
#pragma unroll
        for (int j = 0; j < 2; ++j) {
            const int jcol = bj + wn + j * 16 + lm;
#pragma unroll
            for (int r = 0; r < 4; ++r) {
                const int irow = bi + wm + i * 16 + quad * 4 + r;
                const float lv = left[b * N_SEQ + irow];
                const float rv = right[b * N_SEQ + irow];
                const float dterm = (jcol >= irow) ? lv : rv;
                float v = fmaf(al, acc[i][j][r], fmaf(be, dterm, ga));
                v = fminf(fmaxf(v, -16.f), 14.f);
                raw[((size_t)b * N_SEQ + irow) * N_SEQ + jcol] = v;
            }
        }
}

// ---------------------------------------------------------------------------
// Kernel 3: finalize, one WAVE per (b,i) row.  Block 256 thr = 4 waves,
// grid (96, 8) = 768 blocks.  Segmented c-major scan: lane owns cols
// j = c*64+lane (c=0..5) -> fully coalesced loads/stores; 6 wave-scans give
// the exclusive prefix P; analytic mask intervals:
//   i<j: (P[j]-P[i+1]) + (P[i]-P[max(2i-j+1,0)])
//   i>j: (P[i]-P[j+1]) + (P[min(2i-j+1,N)]-P[i+1])
// masking_matrix input never touched.  (known-good)
// ---------------------------------------------------------------------------
__global__ __launch_bounds__(256) void finalize(
    const float* __restrict__ raw, const float* __restrict__ mask,
    float* __restrict__ out_r, float* __restrict__ out_am)
{
    const int n = N_SEQ;
    __shared__ float P[4][N_SEQ + 1];   // per-wave prefix array
    const int wv = threadIdx.x >> 6, lane = threadIdx.x & 63;
    const int b = blockIdx.y;
    const int i = blockIdx.x * 4 + wv;
    const float* rowp = raw + ((size_t)b * n + i) * n;

    float x[6], l1[6];
#pragma unroll
    for (int c = 0; c < 6; ++c) {
        x[c]  = rowp[c * 64 + lane];
        l1[c] = -log1pf(expf(x[c]));     // log(1 - sigmoid(x))
    }
    // segmented scan: per c, wave-inclusive-scan; carry segment totals.
    float base = 0.f;
#pragma unroll
    for (int c = 0; c < 6; ++c) {
        float incl = l1[c];
#pragma unroll
        for (int off = 1; off < 64; off <<= 1) {
            const float tt = __shfl_up(incl, off);
            if (lane >= off) incl += tt;
        }
        P[wv][1 + c * 64 + lane] = base + incl;
        base += __shfl(incl, 63);        // segment total broadcast
    }
    if (lane == 0) P[wv][0] = 0.f;
    __syncthreads();

    const float mi = mask[b * n + i];
#pragma unroll
    for (int c = 0; c < 6; ++c) {
        const int j = c * 64 + lane;
        float s = 0.f;
        if (i < j) {
            int lo2 = 2 * i - j + 1; if (lo2 < 0) lo2 = 0;
            s = (P[wv][j] - P[wv][i + 1]) + (P[wv][i] - P[wv][lo2]);
        } else if (i > j) {
            int hi2 = 2 * i - j + 1; if (hi2 > n) hi2 = n;
            s = (P[wv][i] - P[wv][j + 1]) + (P[wv][hi2] - P[wv][i + 1]);
        }
        float r = s + (x[c] + l1[c]);    // lp = x + l1
        if (i == j) r -= 10000.f;
        const size_t o = ((size_t)b * n + i) * n + j;
        out_r[o]  = r;
        out_am[o] = mi * mask[b * n + j];
    }
}

// ---------------------------------------------------------------------------
extern "C" void kernel_launch(void* const* d_in, const int* in_sizes, int n_in,
                              void* d_out, int out_size, void* d_ws, size_t ws_size,
                              hipStream_t stream) {
    const float* h     = (const float*)d_in[0];
    const float* mask  = (const float*)d_in[1];
    const float* Wq    = (const float*)d_in[2];
    const float* bq    = (const float*)d_in[3];
    const float* Wk    = (const float*)d_in[4];
    const float* wlr   = (const float*)d_in[5];
    const float* blr   = (const float*)d_in[6];
    const float* wrl   = (const float*)d_in[7];
    const float* brl   = (const float*)d_in[8];
    const float* alpha = (const float*)d_in[9];
    const float* beta  = (const float*)d_in[10];
    const float* gamma = (const float*)d_in[11];
    // d_in[12] (masking_matrix) intentionally unused: analytic k-intervals +
    // prefix sum replace the O(N^3) einsum.

    unsigned short* h_bf  = (unsigned short*)d_ws;                 // 3072x512
    unsigned short* w_bf  = h_bf + (size_t)M_ROWS * DIM;           // 1024x512
    unsigned short* qk_bf = w_bf + (size_t)QK_COLS * DIM;          // 3072x1024
    float* left  = (float*)(qk_bf + (size_t)M_ROWS * QK_COLS);     // 3072
    float* right = left + M_ROWS;                                  // 3072
    float* raw   = right + M_ROWS;                                 // 8*384*384

    float* out_r  = (float*)d_out;
    float* out_am = out_r + (size_t)BATCH * N_SEQ * N_SEQ;

    prep<<<1024, 256, 0, stream>>>(h, Wq, Wk, wlr, blr, wrl, brl,
                                   h_bf, w_bf, left, right);
    dim3 g1(M_ROWS / 64, QK_COLS / 64);         // 48 x 16
    qk_gemm<<<g1, 256, 0, stream>>>(h_bf, w_bf, bq, qk_bf);
    dim3 g2(N_SEQ / 64, N_SEQ / 64, BATCH);     // 6 x 6 x 8
    score_gemm<<<g2, 256, 0, stream>>>(qk_bf, left, right, alpha, beta, gamma, raw);
    dim3 g3(M_ROWS / 4 / BATCH, BATCH);         // 96 x 8 (wave per row)
    finalize<<<g3, 256, 0, stream>>>(raw, mask, out_r, out_am);
}